// Round 1
// baseline (2306.686 us; speedup 1.0000x reference)
//
#include <hip/hip_runtime.h>
#include <float.h>

#define D_DIM 512
#define NC    64
#define NB    200000
#define BS_N  2048
#define NCL   100
#define TK    64

// d_out float offsets
#define O_ORIG 0          // 2048*100
#define O_YPRED 204800    // 2048*100
#define O_L1   409600
#define O_L2   409601
#define O_NORM 409602
#define O_CPRED 409603    // 2048*64

// ws float offsets
#define W_GRAM 0
#define W_GINV 4096
#define W_U    8192
#define W_H    14592
#define W_Q    20992
#define W_S    220992     // 64*200000 floats

// ---------------- K1: gram = C^T C (64x64) ----------------
__global__ void gram_kernel(const float* __restrict__ C, float* __restrict__ gram) {
    int i = blockIdx.x, j = threadIdx.x;
    float s = 0.f;
    for (int k = 0; k < D_DIM; ++k) s = fmaf(C[k*NC + i], C[k*NC + j], s);
    gram[i*NC + j] = s;
}

// ---------------- K2: L_sparse_2, norm_metrics, zero L1 accumulator ----------------
__global__ void scalars_kernel(const float* __restrict__ gram, float* __restrict__ out3) {
    __shared__ float ra[256], rd[256];
    int t = threadIdx.x;
    float sa = 0.f, sd = 0.f;
    for (int idx = t; idx < NC*NC; idx += 256) {
        float g = gram[idx];
        sa += g;
        if (idx % (NC + 1) == 0) sd += g;   // diagonal
    }
    ra[t] = sa; rd[t] = sd;
    __syncthreads();
    for (int s2 = 128; s2 > 0; s2 >>= 1) {
        if (t < s2) { ra[t] += ra[t+s2]; rd[t] += rd[t+s2]; }
        __syncthreads();
    }
    if (t == 0) {
        out3[0] = 0.f;                                // L_sparse_1 accumulator
        out3[1] = (ra[0] - rd[0]) * (1.0f/4096.0f);   // L_sparse_2
        out3[2] = rd[0] * (1.0f/4096.0f);             // norm_metrics
    }
}

// ---------------- K3: Ginv = inv(gram), Gauss-Jordan in LDS ----------------
// gram is strongly diagonally dominant (~42.7 I + ~N(0,1.9) off-diag): no pivoting needed.
__global__ void invert_kernel(const float* __restrict__ gram, float* __restrict__ ginv) {
    __shared__ float A[64][130];  // [64][128] padded
    __shared__ float m[64];
    int t = threadIdx.x;
    for (int idx = t; idx < 64*64; idx += blockDim.x) {
        int r = idx >> 6, c = idx & 63;
        A[r][c]      = gram[idx];
        A[r][64 + c] = (r == c) ? 1.0f : 0.0f;
    }
    __syncthreads();
    for (int k = 0; k < 64; ++k) {
        float inv = 1.0f / A[k][k];
        if (t < 64) m[t] = A[t][k] * inv;   // snapshot multipliers before modifying
        __syncthreads();
        for (int idx = t; idx < 64*128; idx += blockDim.x) {
            int i = idx >> 7, j = idx & 127;
            if (i != k) A[i][j] = fmaf(-m[i], A[k][j], A[i][j]);
        }
        __syncthreads();
    }
    for (int idx = t; idx < 64*64; idx += blockDim.x) {
        int r = idx >> 6, c = idx & 63;
        ginv[idx] = A[r][64 + c] / A[r][r];
    }
}

// ---------------- K4: U = C^T @ w_head (64x100) ----------------
__global__ void u_kernel(const float* __restrict__ C, const float* __restrict__ W,
                         float* __restrict__ U) {
    int i = blockIdx.x, j = threadIdx.x;
    if (j < NCL) {
        float s = 0.f;
        for (int k = 0; k < D_DIM; ++k) s = fmaf(C[k*NC + i], W[k*NCL + j], s);
        U[i*NCL + j] = s;
    }
}

// ---------------- K5: H = Ginv @ U (64x100) ----------------
__global__ void h_kernel(const float* __restrict__ Ginv, const float* __restrict__ U,
                         float* __restrict__ H) {
    int i = blockIdx.x, j = threadIdx.x;
    if (j < NCL) {
        float s = 0.f;
        for (int k = 0; k < NC; ++k) s = fmaf(Ginv[i*NC + k], U[k*NCL + j], s);
        H[i*NCL + j] = s;
    }
}

// ---------------- K6: T = E @ C (2048x64) == concept_pred ----------------
__global__ void t_kernel(const float* __restrict__ E, const float* __restrict__ C,
                         float* __restrict__ T) {
    int row = blockIdx.x * 4 + (threadIdx.x >> 6);
    int c   = threadIdx.x & 63;
    const float* e = E + (size_t)row * D_DIM;
    float s = 0.f;
    #pragma unroll 8
    for (int k = 0; k < D_DIM; ++k) s = fmaf(e[k], C[k*NC + c], s);
    T[row*NC + c] = s;
}

// ---------------- K7: y_pred = T @ H (2048x100) ----------------
__global__ void ypred_kernel(const float* __restrict__ T, const float* __restrict__ H,
                             float* __restrict__ Y) {
    int id = blockIdx.x * blockDim.x + threadIdx.x;
    if (id >= BS_N * NCL) return;
    int row = id / NCL, col = id % NCL;
    float s = 0.f;
    #pragma unroll 8
    for (int k = 0; k < NC; ++k) s = fmaf(T[row*NC + k], H[k*NCL + col], s);
    Y[id] = s;
}

// ---------------- K8: orig_pred = E @ w_head (2048x100) ----------------
__global__ void opred_kernel(const float* __restrict__ E, const float* __restrict__ W,
                             float* __restrict__ O) {
    int id = blockIdx.x * blockDim.x + threadIdx.x;
    if (id >= BS_N * NCL) return;
    int row = id / NCL, col = id % NCL;
    const float* e = E + (size_t)row * D_DIM;
    float s = 0.f;
    #pragma unroll 8
    for (int k = 0; k < D_DIM; ++k) s = fmaf(e[k], W[k*NCL + col], s);
    O[id] = s;
}

// ---------------- K9: scores s[c][r] = |b_r|^2 - 2 c_c . b_r ----------------
// 64x64 output tile per block, K=512 in chunks of 16. Bank read exactly once;
// per-row sum-of-squares fused into staging.
__global__ void score_kernel(const float* __restrict__ Bk, const float* __restrict__ C,
                             float* __restrict__ S, float* __restrict__ Q) {
    __shared__ float Bl[16][68];   // [k][row] (+4 pad)
    __shared__ float Cl[16][68];   // [k][concept]
    __shared__ float qtmp[256];
    __shared__ float qred[64];
    int t = threadIdx.x;
    int r0 = blockIdx.x * 64;
    int trow = t >> 2, tkq = t & 3;       // staging: row, k-quad
    int tx = t & 15, ty = t >> 4;         // compute: row-group / concept-group; staging C: (k=ty, cquad=tx)
    float acc[4][4];
    #pragma unroll
    for (int a = 0; a < 4; ++a)
        #pragma unroll
        for (int b = 0; b < 4; ++b) acc[a][b] = 0.f;
    float qpart = 0.f;
    const float* brow = Bk + (size_t)(r0 + trow) * D_DIM + tkq * 4;

    for (int kk = 0; kk < D_DIM; kk += 16) {
        float4 bv = *(const float4*)(brow + kk);
        float4 cv = *(const float4*)(C + (size_t)(kk + ty) * NC + tx * 4);
        qpart = fmaf(bv.x, bv.x, qpart);
        qpart = fmaf(bv.y, bv.y, qpart);
        qpart = fmaf(bv.z, bv.z, qpart);
        qpart = fmaf(bv.w, bv.w, qpart);
        __syncthreads();                  // WAR: previous tile fully consumed
        Bl[tkq*4 + 0][trow] = bv.x;
        Bl[tkq*4 + 1][trow] = bv.y;
        Bl[tkq*4 + 2][trow] = bv.z;
        Bl[tkq*4 + 3][trow] = bv.w;
        *(float4*)(&Cl[ty][tx*4]) = cv;
        __syncthreads();
        #pragma unroll
        for (int k = 0; k < 16; ++k) {
            float4 b4 = *(const float4*)(&Bl[k][tx*4]);
            float4 c4 = *(const float4*)(&Cl[k][ty*4]);
            float bb[4] = {b4.x, b4.y, b4.z, b4.w};
            float cc[4] = {c4.x, c4.y, c4.z, c4.w};
            #pragma unroll
            for (int ci = 0; ci < 4; ++ci)
                #pragma unroll
                for (int ri = 0; ri < 4; ++ri)
                    acc[ci][ri] = fmaf(cc[ci], bb[ri], acc[ci][ri]);
        }
    }
    qtmp[t] = qpart;
    __syncthreads();
    if (t < 64) {
        float q = qtmp[4*t] + qtmp[4*t+1] + qtmp[4*t+2] + qtmp[4*t+3];
        qred[t] = q;
        Q[r0 + t] = q;
    }
    __syncthreads();
    #pragma unroll
    for (int ci = 0; ci < 4; ++ci) {
        int c = ty*4 + ci;
        float4 sv;
        sv.x = qred[tx*4+0] - 2.f*acc[ci][0];
        sv.y = qred[tx*4+1] - 2.f*acc[ci][1];
        sv.z = qred[tx*4+2] - 2.f*acc[ci][2];
        sv.w = qred[tx*4+3] - 2.f*acc[ci][3];
        *(float4*)(&S[(size_t)c*NB + r0 + tx*4]) = sv;
    }
}

// ---------------- K10: per-concept top-64 smallest + dot-sum -> L_sparse_1 ----------------
__global__ void select_kernel(const float* __restrict__ S, const float* __restrict__ Q,
                              float* __restrict__ out_l1) {
    const int c = blockIdx.x, t = threadIdx.x;
    const float* s = S + (size_t)c * NB;
    __shared__ float rmn[256], rmx[256];
    // pass 1: min/max
    float mn = FLT_MAX, mx = -FLT_MAX;
    for (int i = t; i < NB; i += 256) {
        float v = s[i];
        mn = fminf(mn, v); mx = fmaxf(mx, v);
    }
    rmn[t] = mn; rmx[t] = mx;
    __syncthreads();
    for (int s2 = 128; s2 > 0; s2 >>= 1) {
        if (t < s2) { rmn[t] = fminf(rmn[t], rmn[t+s2]); rmx[t] = fmaxf(rmx[t], rmx[t+s2]); }
        __syncthreads();
    }
    __shared__ float smn, sinvw;
    __shared__ int sB, scnt;
    if (t == 0) {
        smn = rmn[0];
        float w = rmx[0] - rmn[0];
        sinvw = (w > 0.f) ? (1024.0f / w) : 0.f;
        scnt = 0;
    }
    __syncthreads();
    float lmn = smn, linvw = sinvw;
    // pass 2: 1024-bin linear histogram
    __shared__ unsigned hist[1024];
    for (int i = t; i < 1024; i += 256) hist[i] = 0u;
    __syncthreads();
    for (int i = t; i < NB; i += 256) {
        int b = (int)((s[i] - lmn) * linvw);
        b = min(b, 1023);
        atomicAdd(&hist[b], 1u);
    }
    __syncthreads();
    if (t == 0) {
        unsigned cum = 0; int B = 1023;
        for (int b = 0; b < 1024; ++b) { cum += hist[b]; if (cum >= TK) { B = b; break; } }
        sB = B;
    }
    __syncthreads();
    // pass 3: collect candidates (bin <= B): superset of the 64 smallest
    const int CAP = 2048;
    __shared__ float cs[CAP], cd[CAP];
    int B = sB;
    for (int i = t; i < NB; i += 256) {
        float v = s[i];
        int b = (int)((v - lmn) * linvw);
        b = min(b, 1023);
        if (b <= B) {
            int idx = atomicAdd(&scnt, 1);
            if (idx < CAP) { cs[idx] = v; cd[idx] = (Q[i] - v) * 0.5f; }  // recover dot
        }
    }
    __syncthreads();
    int M = min(scnt, CAP);
    // exact: 64x block-parallel argmin
    __shared__ float bvals[256];
    __shared__ int bidx[256];
    __shared__ float sdsum;
    if (t == 0) sdsum = 0.f;
    for (int j = 0; j < TK; ++j) {
        float bv = FLT_MAX; int bi = -1;
        for (int i = t; i < M; i += 256) {
            if (cs[i] < bv) { bv = cs[i]; bi = i; }
        }
        bvals[t] = bv; bidx[t] = bi;
        __syncthreads();
        if (t == 0) {
            float best = FLT_MAX; int besti = -1;
            for (int i = 0; i < 256; ++i)
                if (bvals[i] < best) { best = bvals[i]; besti = bidx[i]; }
            if (besti >= 0) { sdsum += cd[besti]; cs[besti] = FLT_MAX; }
        }
        __syncthreads();
    }
    if (t == 0) atomicAdd(out_l1, sdsum * (1.0f/4096.0f));
}

extern "C" void kernel_launch(void* const* d_in, const int* in_sizes, int n_in,
                              void* d_out, int out_size, void* d_ws, size_t ws_size,
                              hipStream_t stream) {
    const float* C  = (const float*)d_in[0];   // (512, 64)
    const float* E  = (const float*)d_in[1];   // (2048, 512)
    const float* Bk = (const float*)d_in[2];   // (200000, 512)
    const float* W  = (const float*)d_in[3];   // (512, 100)
    float* out = (float*)d_out;
    float* ws  = (float*)d_ws;

    float* gram = ws + W_GRAM;
    float* ginv = ws + W_GINV;
    float* U    = ws + W_U;
    float* H    = ws + W_H;
    float* Q    = ws + W_Q;
    float* S    = ws + W_S;

    gram_kernel  <<<64,   64,  0, stream>>>(C, gram);
    scalars_kernel<<<1,   256, 0, stream>>>(gram, out + O_L1);
    invert_kernel<<<1,    512, 0, stream>>>(gram, ginv);
    u_kernel     <<<64,   128, 0, stream>>>(C, W, U);
    h_kernel     <<<64,   128, 0, stream>>>(ginv, U, H);
    t_kernel     <<<512,  256, 0, stream>>>(E, C, out + O_CPRED);
    ypred_kernel <<<800,  256, 0, stream>>>(out + O_CPRED, H, out + O_YPRED);
    opred_kernel <<<800,  256, 0, stream>>>(E, W, out + O_ORIG);
    score_kernel <<<NB/64, 256, 0, stream>>>(Bk, C, S, Q);
    select_kernel<<<NC,   256, 0, stream>>>(S, Q, out + O_L1);
}

// Round 2
// 1030.464 us; speedup vs baseline: 2.2385x; 2.2385x over previous
//
#include <hip/hip_runtime.h>
#include <float.h>

#define D_DIM 512
#define NC    64
#define NB    200000
#define BS_N  2048
#define NCL   100
#define TK    64
#define CAP   2048      // candidate capacity per concept (bin == B)

// d_out float offsets
#define O_ORIG 0          // 2048*100
#define O_YPRED 204800    // 2048*100
#define O_L1   409600
#define O_L2   409601
#define O_NORM 409602
#define O_CPRED 409603    // 2048*64

// ws float offsets
#define W_GRAM  0         // 4096
#define W_GINV  4096      // 4096
#define W_U     8192      // 6400
#define W_H     14592     // 6400
#define W_Q     20992     // 200000
#define W_MIN   220992    // 64 (ordered-uint min per concept)
#define W_MAX   221056    // 64
#define W_BIN   221120    // 64 (chosen bin B per concept)
#define W_NBEL  221184    // 64 (count strictly below B)
#define W_CCNT  221248    // 64 (candidate counts)
#define W_PSUM  221312    // 64 (dot partial sums, float atomics)
#define W_HIST  221376    // 64*1024 = 65536
#define W_CANDV 286912    // 64*2048 = 131072
#define W_CANDD 417984    // 131072
#define W_S     549056    // 64*200000 = 12.8M floats (ends ~53.4 MB)

__device__ inline unsigned f2ord(float f) {
    unsigned u = __float_as_uint(f);
    return (u & 0x80000000u) ? ~u : (u | 0x80000000u);
}
__device__ inline float ord2f(unsigned u) {
    return (u & 0x80000000u) ? __uint_as_float(u & 0x7fffffffu) : __uint_as_float(~u);
}

// ---------------- K1: gram = C^T C (64x64) ----------------
__global__ void gram_kernel(const float* __restrict__ C, float* __restrict__ gram) {
    int i = blockIdx.x, j = threadIdx.x;
    float s = 0.f;
    for (int k = 0; k < D_DIM; ++k) s = fmaf(C[k*NC + i], C[k*NC + j], s);
    gram[i*NC + j] = s;
}

// ---------------- K2: L_sparse_2, norm_metrics, zero L1 accumulator ----------------
__global__ void scalars_kernel(const float* __restrict__ gram, float* __restrict__ out3) {
    __shared__ float ra[256], rd[256];
    int t = threadIdx.x;
    float sa = 0.f, sd = 0.f;
    for (int idx = t; idx < NC*NC; idx += 256) {
        float g = gram[idx];
        sa += g;
        if (idx % (NC + 1) == 0) sd += g;   // diagonal
    }
    ra[t] = sa; rd[t] = sd;
    __syncthreads();
    for (int s2 = 128; s2 > 0; s2 >>= 1) {
        if (t < s2) { ra[t] += ra[t+s2]; rd[t] += rd[t+s2]; }
        __syncthreads();
    }
    if (t == 0) {
        out3[0] = 0.f;                                // L_sparse_1 accumulator
        out3[1] = (ra[0] - rd[0]) * (1.0f/4096.0f);   // L_sparse_2
        out3[2] = rd[0] * (1.0f/4096.0f);             // norm_metrics
    }
}

// ---------------- K3: Ginv = inv(gram), Gauss-Jordan in LDS ----------------
__global__ void invert_kernel(const float* __restrict__ gram, float* __restrict__ ginv) {
    __shared__ float A[64][130];
    __shared__ float m[64];
    int t = threadIdx.x;
    for (int idx = t; idx < 64*64; idx += blockDim.x) {
        int r = idx >> 6, c = idx & 63;
        A[r][c]      = gram[idx];
        A[r][64 + c] = (r == c) ? 1.0f : 0.0f;
    }
    __syncthreads();
    for (int k = 0; k < 64; ++k) {
        float inv = 1.0f / A[k][k];
        if (t < 64) m[t] = A[t][k] * inv;
        __syncthreads();
        for (int idx = t; idx < 64*128; idx += blockDim.x) {
            int i = idx >> 7, j = idx & 127;
            if (i != k) A[i][j] = fmaf(-m[i], A[k][j], A[i][j]);
        }
        __syncthreads();
    }
    for (int idx = t; idx < 64*64; idx += blockDim.x) {
        int r = idx >> 6, c = idx & 63;
        ginv[idx] = A[r][64 + c] / A[r][r];
    }
}

// ---------------- K4: U = C^T @ w_head (64x100) ----------------
__global__ void u_kernel(const float* __restrict__ C, const float* __restrict__ W,
                         float* __restrict__ U) {
    int i = blockIdx.x, j = threadIdx.x;
    if (j < NCL) {
        float s = 0.f;
        for (int k = 0; k < D_DIM; ++k) s = fmaf(C[k*NC + i], W[k*NCL + j], s);
        U[i*NCL + j] = s;
    }
}

// ---------------- K5: H = Ginv @ U (64x100) ----------------
__global__ void h_kernel(const float* __restrict__ Ginv, const float* __restrict__ U,
                         float* __restrict__ H) {
    int i = blockIdx.x, j = threadIdx.x;
    if (j < NCL) {
        float s = 0.f;
        for (int k = 0; k < NC; ++k) s = fmaf(Ginv[i*NC + k], U[k*NCL + j], s);
        H[i*NCL + j] = s;
    }
}

// ---------------- K6: T = E @ C (2048x64) == concept_pred ----------------
__global__ void t_kernel(const float* __restrict__ E, const float* __restrict__ C,
                         float* __restrict__ T) {
    int row = blockIdx.x * 4 + (threadIdx.x >> 6);
    int c   = threadIdx.x & 63;
    const float* e = E + (size_t)row * D_DIM;
    float s = 0.f;
    #pragma unroll 8
    for (int k = 0; k < D_DIM; ++k) s = fmaf(e[k], C[k*NC + c], s);
    T[row*NC + c] = s;
}

// ---------------- K7: y_pred = T @ H (2048x100) ----------------
__global__ void ypred_kernel(const float* __restrict__ T, const float* __restrict__ H,
                             float* __restrict__ Y) {
    int id = blockIdx.x * blockDim.x + threadIdx.x;
    if (id >= BS_N * NCL) return;
    int row = id / NCL, col = id % NCL;
    float s = 0.f;
    #pragma unroll 8
    for (int k = 0; k < NC; ++k) s = fmaf(T[row*NC + k], H[k*NCL + col], s);
    Y[id] = s;
}

// ---------------- K8: orig_pred = E @ w_head (2048x100) ----------------
__global__ void opred_kernel(const float* __restrict__ E, const float* __restrict__ W,
                             float* __restrict__ O) {
    int id = blockIdx.x * blockDim.x + threadIdx.x;
    if (id >= BS_N * NCL) return;
    int row = id / NCL, col = id % NCL;
    const float* e = E + (size_t)row * D_DIM;
    float s = 0.f;
    #pragma unroll 8
    for (int k = 0; k < D_DIM; ++k) s = fmaf(e[k], W[k*NCL + col], s);
    O[id] = s;
}

// ---------------- K9: scores s[c][r] = |b_r|^2 - 2 c_c . b_r  (+ per-concept min/max) ----------------
__global__ void score_kernel(const float* __restrict__ Bk, const float* __restrict__ C,
                             float* __restrict__ S, float* __restrict__ Q,
                             unsigned* __restrict__ mn_ord, unsigned* __restrict__ mx_ord) {
    __shared__ float Bl[16][68];
    __shared__ float Cl[16][68];
    __shared__ float qtmp[256];
    __shared__ float qred[64];
    int t = threadIdx.x;
    int r0 = blockIdx.x * 64;
    int trow = t >> 2, tkq = t & 3;
    int tx = t & 15, ty = t >> 4;
    float acc[4][4];
    #pragma unroll
    for (int a = 0; a < 4; ++a)
        #pragma unroll
        for (int b = 0; b < 4; ++b) acc[a][b] = 0.f;
    float qpart = 0.f;
    const float* brow = Bk + (size_t)(r0 + trow) * D_DIM + tkq * 4;

    for (int kk = 0; kk < D_DIM; kk += 16) {
        float4 bv = *(const float4*)(brow + kk);
        float4 cv = *(const float4*)(C + (size_t)(kk + ty) * NC + tx * 4);
        qpart = fmaf(bv.x, bv.x, qpart);
        qpart = fmaf(bv.y, bv.y, qpart);
        qpart = fmaf(bv.z, bv.z, qpart);
        qpart = fmaf(bv.w, bv.w, qpart);
        __syncthreads();
        Bl[tkq*4 + 0][trow] = bv.x;
        Bl[tkq*4 + 1][trow] = bv.y;
        Bl[tkq*4 + 2][trow] = bv.z;
        Bl[tkq*4 + 3][trow] = bv.w;
        *(float4*)(&Cl[ty][tx*4]) = cv;
        __syncthreads();
        #pragma unroll
        for (int k = 0; k < 16; ++k) {
            float4 b4 = *(const float4*)(&Bl[k][tx*4]);
            float4 c4 = *(const float4*)(&Cl[k][ty*4]);
            float bb[4] = {b4.x, b4.y, b4.z, b4.w};
            float cc[4] = {c4.x, c4.y, c4.z, c4.w};
            #pragma unroll
            for (int ci = 0; ci < 4; ++ci)
                #pragma unroll
                for (int ri = 0; ri < 4; ++ri)
                    acc[ci][ri] = fmaf(cc[ci], bb[ri], acc[ci][ri]);
        }
    }
    qtmp[t] = qpart;
    __syncthreads();
    if (t < 64) {
        float q = qtmp[4*t] + qtmp[4*t+1] + qtmp[4*t+2] + qtmp[4*t+3];
        qred[t] = q;
        Q[r0 + t] = q;
    }
    __syncthreads();
    #pragma unroll
    for (int ci = 0; ci < 4; ++ci) {
        int c = ty*4 + ci;
        float4 sv;
        sv.x = qred[tx*4+0] - 2.f*acc[ci][0];
        sv.y = qred[tx*4+1] - 2.f*acc[ci][1];
        sv.z = qred[tx*4+2] - 2.f*acc[ci][2];
        sv.w = qred[tx*4+3] - 2.f*acc[ci][3];
        *(float4*)(&S[(size_t)c*NB + r0 + tx*4]) = sv;
        // per-concept min/max: reduce over the 16 tx lanes (64 rows of this block)
        float mn4 = fminf(fminf(sv.x, sv.y), fminf(sv.z, sv.w));
        float mx4 = fmaxf(fmaxf(sv.x, sv.y), fmaxf(sv.z, sv.w));
        #pragma unroll
        for (int o = 1; o < 16; o <<= 1) {
            mn4 = fminf(mn4, __shfl_xor(mn4, o));
            mx4 = fmaxf(mx4, __shfl_xor(mx4, o));
        }
        if (tx == 0) {
            atomicMin(&mn_ord[c], f2ord(mn4));
            atomicMax(&mx_ord[c], f2ord(mx4));
        }
    }
}

// ---------------- K10: per-concept 1024-bin histogram ----------------
__global__ void hist_kernel(const float* __restrict__ S,
                            const unsigned* __restrict__ mn_ord, const unsigned* __restrict__ mx_ord,
                            unsigned* __restrict__ hist) {
    __shared__ unsigned h[1024];
    int c = blockIdx.y, t = threadIdx.x;
    for (int i = t; i < 1024; i += 256) h[i] = 0u;
    float mnf = ord2f(mn_ord[c]);
    float mxf = ord2f(mx_ord[c]);
    float invw = (mxf > mnf) ? 1024.0f / (mxf - mnf) : 0.f;
    __syncthreads();
    const float4* s4 = (const float4*)(S + (size_t)c * NB);
    int base = blockIdx.x * 1024;
    #pragma unroll
    for (int j = 0; j < 4; ++j) {
        int idx = base + j*256 + t;
        if (idx < NB/4) {
            float4 v = s4[idx];
            float vv[4] = {v.x, v.y, v.z, v.w};
            #pragma unroll
            for (int e = 0; e < 4; ++e) {
                int b = (int)((vv[e] - mnf) * invw);
                b = b < 0 ? 0 : (b > 1023 ? 1023 : b);
                atomicAdd(&h[b], 1u);
            }
        }
    }
    __syncthreads();
    for (int i = t; i < 1024; i += 256)
        if (h[i]) atomicAdd(&hist[c*1024 + i], h[i]);
}

// ---------------- K11: per-concept scan -> bin B, count below ----------------
__global__ void scan_kernel(const unsigned* __restrict__ hist,
                            int* __restrict__ binB, int* __restrict__ nbel) {
    int c = threadIdx.x;
    if (c >= NC) return;
    unsigned cum = 0; int B = 1023; unsigned below = 0;
    for (int b = 0; b < 1024; ++b) {
        unsigned hb = hist[c*1024 + b];
        if (cum + hb >= TK) { B = b; below = cum; break; }
        cum += hb;
    }
    binB[c] = B;
    nbel[c] = (int)below;
}

// ---------------- K12: collect — sum dots below B, gather bin-B candidates ----------------
__global__ void collect_kernel(const float* __restrict__ S, const float* __restrict__ Q,
                               const unsigned* __restrict__ mn_ord, const unsigned* __restrict__ mx_ord,
                               const int* __restrict__ binB,
                               int* __restrict__ ccnt, float* __restrict__ candv,
                               float* __restrict__ candd, float* __restrict__ psum) {
    __shared__ float red[256];
    int c = blockIdx.y, t = threadIdx.x;
    float mnf = ord2f(mn_ord[c]);
    float mxf = ord2f(mx_ord[c]);
    float invw = (mxf > mnf) ? 1024.0f / (mxf - mnf) : 0.f;
    int B = binB[c];
    const float4* s4 = (const float4*)(S + (size_t)c * NB);
    int base = blockIdx.x * 1024;
    float dsum = 0.f;
    #pragma unroll
    for (int j = 0; j < 4; ++j) {
        int idx = base + j*256 + t;
        if (idx < NB/4) {
            float4 v = s4[idx];
            float vv[4] = {v.x, v.y, v.z, v.w};
            #pragma unroll
            for (int e = 0; e < 4; ++e) {
                int b = (int)((vv[e] - mnf) * invw);
                b = b < 0 ? 0 : (b > 1023 ? 1023 : b);
                if (b < B) {
                    dsum += (Q[idx*4 + e] - vv[e]) * 0.5f;
                } else if (b == B) {
                    int p = atomicAdd(&ccnt[c], 1);
                    if (p < CAP) {
                        candv[c*CAP + p] = vv[e];
                        candd[c*CAP + p] = (Q[idx*4 + e] - vv[e]) * 0.5f;
                    }
                }
            }
        }
    }
    red[t] = dsum;
    __syncthreads();
    for (int s2 = 128; s2 > 0; s2 >>= 1) {
        if (t < s2) red[t] += red[t+s2];
        __syncthreads();
    }
    if (t == 0 && red[0] != 0.f) atomicAdd(&psum[c], red[0]);
}

// ---------------- K13: exact top among bin-B candidates, finish L_sparse_1 ----------------
__global__ void final_kernel(const int* __restrict__ binB, const int* __restrict__ nbel,
                             const int* __restrict__ ccnt, const float* __restrict__ candv,
                             const float* __restrict__ candd, const float* __restrict__ psum,
                             float* __restrict__ out_l1) {
    __shared__ float v[CAP];
    __shared__ float dd[CAP];
    int c = blockIdx.x, t = threadIdx.x;   // 64 threads = 1 wave
    int M = ccnt[c]; if (M > CAP) M = CAP;
    int r = TK - nbel[c]; if (r > M) r = M;
    for (int i = t; i < M; i += 64) { v[i] = candv[c*CAP + i]; dd[i] = candd[c*CAP + i]; }
    __syncthreads();
    float sum = 0.f;
    for (int j = 0; j < r; ++j) {
        float bv = FLT_MAX; int bi = -1;
        for (int i = t; i < M; i += 64)
            if (v[i] < bv) { bv = v[i]; bi = i; }
        #pragma unroll
        for (int o = 32; o > 0; o >>= 1) {
            float ov = __shfl_down(bv, o);
            int   oi = __shfl_down(bi, o);
            if (ov < bv) { bv = ov; bi = oi; }
        }
        bi = __shfl(bi, 0);
        if (t == 0 && bi >= 0) { sum += dd[bi]; v[bi] = FLT_MAX; }
        __syncthreads();
    }
    if (t == 0) atomicAdd(out_l1, (sum + psum[c]) * (1.0f/4096.0f));
}

extern "C" void kernel_launch(void* const* d_in, const int* in_sizes, int n_in,
                              void* d_out, int out_size, void* d_ws, size_t ws_size,
                              hipStream_t stream) {
    const float* C  = (const float*)d_in[0];   // (512, 64)
    const float* E  = (const float*)d_in[1];   // (2048, 512)
    const float* Bk = (const float*)d_in[2];   // (200000, 512)
    const float* W  = (const float*)d_in[3];   // (512, 100)
    float* out = (float*)d_out;
    float* ws  = (float*)d_ws;

    float*    gram  = ws + W_GRAM;
    float*    ginv  = ws + W_GINV;
    float*    U     = ws + W_U;
    float*    H     = ws + W_H;
    float*    Q     = ws + W_Q;
    unsigned* mnord = (unsigned*)(ws + W_MIN);
    unsigned* mxord = (unsigned*)(ws + W_MAX);
    int*      binB  = (int*)(ws + W_BIN);
    int*      nbel  = (int*)(ws + W_NBEL);
    int*      ccnt  = (int*)(ws + W_CCNT);
    float*    psum  = ws + W_PSUM;
    unsigned* hist  = (unsigned*)(ws + W_HIST);
    float*    candv = ws + W_CANDV;
    float*    candd = ws + W_CANDD;
    float*    S     = ws + W_S;

    // init scratch (ws is re-poisoned 0xAA before every launch)
    hipMemsetAsync(mnord, 0xFF, NC*4, stream);          // ordered-uint min identity
    hipMemsetAsync(mxord, 0x00, NC*4, stream);          // ordered-uint max identity
    hipMemsetAsync(hist,  0x00, NC*1024*4, stream);
    hipMemsetAsync(ccnt,  0x00, NC*4, stream);
    hipMemsetAsync(psum,  0x00, NC*4, stream);

    gram_kernel   <<<64,   64,  0, stream>>>(C, gram);
    scalars_kernel<<<1,    256, 0, stream>>>(gram, out + O_L1);
    invert_kernel <<<1,    512, 0, stream>>>(gram, ginv);
    u_kernel      <<<64,   128, 0, stream>>>(C, W, U);
    h_kernel      <<<64,   128, 0, stream>>>(ginv, U, H);
    t_kernel      <<<512,  256, 0, stream>>>(E, C, out + O_CPRED);
    ypred_kernel  <<<800,  256, 0, stream>>>(out + O_CPRED, H, out + O_YPRED);
    opred_kernel  <<<800,  256, 0, stream>>>(E, W, out + O_ORIG);
    score_kernel  <<<NB/64, 256, 0, stream>>>(Bk, C, S, Q, mnord, mxord);

    dim3 hgrid(49, 64);  // 49*1024 float4 >= 50000 per concept
    hist_kernel   <<<hgrid, 256, 0, stream>>>(S, mnord, mxord, hist);
    scan_kernel   <<<1,    64,  0, stream>>>(hist, binB, nbel);
    collect_kernel<<<hgrid, 256, 0, stream>>>(S, Q, mnord, mxord, binB, ccnt, candv, candd, psum);
    final_kernel  <<<NC,   64,  0, stream>>>(binB, nbel, ccnt, candv, candd, psum, out + O_L1);
}

// Round 3
// 827.234 us; speedup vs baseline: 2.7884x; 1.2457x over previous
//
#include <hip/hip_runtime.h>
#include <float.h>

#define D_DIM 512
#define NC    64
#define NB    200000
#define BS_N  2048
#define NCL   100
#define TK    64
#define CAP   2048      // candidate capacity per concept (bin == B)

// d_out float offsets
#define O_ORIG 0          // 2048*100
#define O_YPRED 204800    // 2048*100
#define O_L1   409600
#define O_L2   409601
#define O_NORM 409602
#define O_CPRED 409603    // 2048*64

// ws float offsets
#define W_GRAM  0         // 4096
#define W_GINV  4096      // 4096
#define W_U     8192      // 6400
#define W_H     14592     // 6400
#define W_Q     20992     // 200000
#define W_MIN   220992    // 64 (ordered-uint min per concept)
#define W_MAX   221056    // 64
#define W_BIN   221120    // 64
#define W_NBEL  221184    // 64
#define W_CCNT  221248    // 64
#define W_PSUM  221312    // 64
#define W_HIST  221376    // 64*1024
#define W_CANDV 286912    // 64*2048
#define W_CANDD 417984    // 131072
#define W_PACKA 549056    // 32768 bf16 = 16384 floats (C in A-frag layout)
#define W_PACKB 565440    // 90112 bf16 = 45056 floats ([C|W] in A-frag layout)
#define W_S     610496    // 64*200000 floats

typedef __attribute__((ext_vector_type(8))) short bf16x8;
typedef __attribute__((ext_vector_type(4))) float f32x4;

__device__ inline unsigned f2ord(float f) {
    unsigned u = __float_as_uint(f);
    return (u & 0x80000000u) ? ~u : (u | 0x80000000u);
}
__device__ inline float ord2f(unsigned u) {
    return (u & 0x80000000u) ? __uint_as_float(u & 0x7fffffffu) : __uint_as_float(~u);
}
__device__ inline short f2bf(float f) {   // RNE fp32 -> bf16
    unsigned u = __float_as_uint(f);
    u += 0x7FFFu + ((u >> 16) & 1u);
    return (short)(u >> 16);
}

// ---------------- pack: C and [C|W] into MFMA A-fragment bf16 layout ----------------
// A-frag (16x16x32): lane L holds A[m=L&15][k=(L>>4)*8+j], j=0..7.
// PA tile (kt,ci): 64 lanes x 8 bf16, linear dst = tile*512 + lane*8 + j.
__global__ void pack_kernel(const float* __restrict__ C, const float* __restrict__ W,
                            short* __restrict__ PA, short* __restrict__ PB) {
    int b = blockIdx.x, t = threadIdx.x;
    #pragma unroll
    for (int rep = 0; rep < 2; ++rep) {
        int idx = t * 2 + rep;             // 0..511 within tile
        int lane = idx >> 3, j = idx & 7;
        int k, col;
        if (b < 64) {                      // score A: 16 kt x 4 ci
            int kt = b >> 2, ci = b & 3;
            k = kt * 32 + (lane >> 4) * 8 + j;
            col = ci * 16 + (lane & 15);
            PA[b * 512 + idx] = f2bf(C[k * NC + col]);
        } else {                           // ecw A: 16 kt x 11 ci (cols: 64 C + 100 W + 12 pad)
            int bb = b - 64;
            int kt = bb / 11, ci = bb % 11;
            k = kt * 32 + (lane >> 4) * 8 + j;
            col = ci * 16 + (lane & 15);
            float v = 0.f;
            if (col < 64) v = C[k * NC + col];
            else if (col < 164) v = W[k * NCL + (col - 64)];
            PB[bb * 512 + idx] = f2bf(v);
        }
    }
}

// ---------------- K1: gram = C^T C (64x64) ----------------
__global__ void gram_kernel(const float* __restrict__ C, float* __restrict__ gram) {
    int i = blockIdx.x, j = threadIdx.x;
    float s = 0.f;
    for (int k = 0; k < D_DIM; ++k) s = fmaf(C[k*NC + i], C[k*NC + j], s);
    gram[i*NC + j] = s;
}

// ---------------- K2: L_sparse_2, norm_metrics, zero L1 accumulator ----------------
__global__ void scalars_kernel(const float* __restrict__ gram, float* __restrict__ out3) {
    __shared__ float ra[256], rd[256];
    int t = threadIdx.x;
    float sa = 0.f, sd = 0.f;
    for (int idx = t; idx < NC*NC; idx += 256) {
        float g = gram[idx];
        sa += g;
        if (idx % (NC + 1) == 0) sd += g;
    }
    ra[t] = sa; rd[t] = sd;
    __syncthreads();
    for (int s2 = 128; s2 > 0; s2 >>= 1) {
        if (t < s2) { ra[t] += ra[t+s2]; rd[t] += rd[t+s2]; }
        __syncthreads();
    }
    if (t == 0) {
        out3[0] = 0.f;
        out3[1] = (ra[0] - rd[0]) * (1.0f/4096.0f);
        out3[2] = rd[0] * (1.0f/4096.0f);
    }
}

// ---------------- K3: Ginv = inv(gram), Gauss-Jordan in LDS ----------------
__global__ void invert_kernel(const float* __restrict__ gram, float* __restrict__ ginv) {
    __shared__ float A[64][130];
    __shared__ float m[64];
    int t = threadIdx.x;
    for (int idx = t; idx < 64*64; idx += blockDim.x) {
        int r = idx >> 6, c = idx & 63;
        A[r][c]      = gram[idx];
        A[r][64 + c] = (r == c) ? 1.0f : 0.0f;
    }
    __syncthreads();
    for (int k = 0; k < 64; ++k) {
        float inv = 1.0f / A[k][k];
        if (t < 64) m[t] = A[t][k] * inv;
        __syncthreads();
        for (int idx = t; idx < 64*128; idx += blockDim.x) {
            int i = idx >> 7, j = idx & 127;
            if (i != k) A[i][j] = fmaf(-m[i], A[k][j], A[i][j]);
        }
        __syncthreads();
    }
    for (int idx = t; idx < 64*64; idx += blockDim.x) {
        int r = idx >> 6, c = idx & 63;
        ginv[idx] = A[r][64 + c] / A[r][r];
    }
}

// ---------------- K4: U = C^T @ w_head ----------------
__global__ void u_kernel(const float* __restrict__ C, const float* __restrict__ W,
                         float* __restrict__ U) {
    int i = blockIdx.x, j = threadIdx.x;
    if (j < NCL) {
        float s = 0.f;
        for (int k = 0; k < D_DIM; ++k) s = fmaf(C[k*NC + i], W[k*NCL + j], s);
        U[i*NCL + j] = s;
    }
}

// ---------------- K5: H = Ginv @ U ----------------
__global__ void h_kernel(const float* __restrict__ Ginv, const float* __restrict__ U,
                         float* __restrict__ H) {
    int i = blockIdx.x, j = threadIdx.x;
    if (j < NCL) {
        float s = 0.f;
        for (int k = 0; k < NC; ++k) s = fmaf(Ginv[i*NC + k], U[k*NCL + j], s);
        H[i*NCL + j] = s;
    }
}

// ---------------- K6: fused E@[C|W] via bf16 MFMA -> concept_pred, orig_pred ----------------
// M=176 cols (64 C + 100 W + 12 pad), N=2048 rows, K=512. 16 blocks x 128 rows.
__global__ void ecw_kernel(const float* __restrict__ E, const short* __restrict__ PB,
                           float* __restrict__ T, float* __restrict__ O) {
    int t = threadIdx.x, wave = t >> 6, lane = t & 63;
    int quad = lane >> 4, l16 = lane & 15;
    int rbase = blockIdx.x * 128 + wave * 32;
    int row0 = rbase + l16, row1 = rbase + 16 + l16;
    const float* p0 = E + (size_t)row0 * D_DIM + quad * 8;
    const float* p1 = E + (size_t)row1 * D_DIM + quad * 8;

    f32x4 acc[11][2];
    #pragma unroll
    for (int ci = 0; ci < 11; ++ci) { acc[ci][0] = 0.f; acc[ci][1] = 0.f; }

    for (int kt = 0; kt < 16; ++kt) {
        float4 a0 = *(const float4*)(p0 + kt*32);
        float4 b0 = *(const float4*)(p0 + kt*32 + 4);
        float4 a1 = *(const float4*)(p1 + kt*32);
        float4 b1 = *(const float4*)(p1 + kt*32 + 4);
        bf16x8 bf0 = { f2bf(a0.x), f2bf(a0.y), f2bf(a0.z), f2bf(a0.w),
                       f2bf(b0.x), f2bf(b0.y), f2bf(b0.z), f2bf(b0.w) };
        bf16x8 bf1 = { f2bf(a1.x), f2bf(a1.y), f2bf(a1.z), f2bf(a1.w),
                       f2bf(b1.x), f2bf(b1.y), f2bf(b1.z), f2bf(b1.w) };
        #pragma unroll
        for (int ci = 0; ci < 11; ++ci) {
            bf16x8 af = *(const bf16x8*)(PB + ((kt*11 + ci)*64 + lane)*8);
            acc[ci][0] = __builtin_amdgcn_mfma_f32_16x16x32_bf16(af, bf0, acc[ci][0], 0, 0, 0);
            acc[ci][1] = __builtin_amdgcn_mfma_f32_16x16x32_bf16(af, bf1, acc[ci][1], 0, 0, 0);
        }
    }
    #pragma unroll
    for (int ci = 0; ci < 11; ++ci) {
        #pragma unroll
        for (int j = 0; j < 4; ++j) {
            int col = ci*16 + quad*4 + j;
            if (col < 64) {
                T[row0*NC + col] = acc[ci][0][j];
                T[row1*NC + col] = acc[ci][1][j];
            } else if (col < 164) {
                O[row0*NCL + (col-64)] = acc[ci][0][j];
                O[row1*NCL + (col-64)] = acc[ci][1][j];
            }
        }
    }
}

// ---------------- K7: y_pred = T @ H ----------------
__global__ void ypred_kernel(const float* __restrict__ T, const float* __restrict__ H,
                             float* __restrict__ Y) {
    int id = blockIdx.x * blockDim.x + threadIdx.x;
    if (id >= BS_N * NCL) return;
    int row = id / NCL, col = id % NCL;
    float s = 0.f;
    #pragma unroll 8
    for (int k = 0; k < NC; ++k) s = fmaf(T[row*NC + k], H[k*NCL + col], s);
    Y[id] = s;
}

// ---------------- K9: scores via bf16 MFMA: S[c][r] = q[r] - 2 * (C^T B^T)[c][r] ----------------
// M=64 concepts, N=128 rows/block, K=512. B-frags straight from global (no LDS, no barriers in K-loop).
__global__ void score_kernel(const float* __restrict__ Bk, const short* __restrict__ PA,
                             float* __restrict__ S, float* __restrict__ Q,
                             unsigned* __restrict__ mn_ord, unsigned* __restrict__ mx_ord) {
    __shared__ unsigned lmn[64], lmx[64];
    int t = threadIdx.x, wave = t >> 6, lane = t & 63;
    int quad = lane >> 4, l16 = lane & 15;
    if (t < 64) { lmn[t] = 0xFFFFFFFFu; lmx[t] = 0u; }
    __syncthreads();

    int rbase = blockIdx.x * 128 + wave * 32;
    int row0 = rbase + l16, row1 = rbase + 16 + l16;
    bool v0 = row0 < NB, v1 = row1 < NB;
    int r0c = v0 ? row0 : (NB-1), r1c = v1 ? row1 : (NB-1);
    const float* p0 = Bk + (size_t)r0c * D_DIM + quad * 8;
    const float* p1 = Bk + (size_t)r1c * D_DIM + quad * 8;

    f32x4 acc[4][2];
    #pragma unroll
    for (int ci = 0; ci < 4; ++ci) { acc[ci][0] = 0.f; acc[ci][1] = 0.f; }
    float q0 = 0.f, q1 = 0.f;

    for (int kt = 0; kt < 16; ++kt) {
        float4 a0 = *(const float4*)(p0 + kt*32);
        float4 b0 = *(const float4*)(p0 + kt*32 + 4);
        float4 a1 = *(const float4*)(p1 + kt*32);
        float4 b1 = *(const float4*)(p1 + kt*32 + 4);
        q0 = fmaf(a0.x,a0.x, fmaf(a0.y,a0.y, fmaf(a0.z,a0.z, fmaf(a0.w,a0.w, q0))));
        q0 = fmaf(b0.x,b0.x, fmaf(b0.y,b0.y, fmaf(b0.z,b0.z, fmaf(b0.w,b0.w, q0))));
        q1 = fmaf(a1.x,a1.x, fmaf(a1.y,a1.y, fmaf(a1.z,a1.z, fmaf(a1.w,a1.w, q1))));
        q1 = fmaf(b1.x,b1.x, fmaf(b1.y,b1.y, fmaf(b1.z,b1.z, fmaf(b1.w,b1.w, q1))));
        bf16x8 bf0 = { f2bf(a0.x), f2bf(a0.y), f2bf(a0.z), f2bf(a0.w),
                       f2bf(b0.x), f2bf(b0.y), f2bf(b0.z), f2bf(b0.w) };
        bf16x8 bf1 = { f2bf(a1.x), f2bf(a1.y), f2bf(a1.z), f2bf(a1.w),
                       f2bf(b1.x), f2bf(b1.y), f2bf(b1.z), f2bf(b1.w) };
        #pragma unroll
        for (int ci = 0; ci < 4; ++ci) {
            bf16x8 af = *(const bf16x8*)(PA + ((kt*4 + ci)*64 + lane)*8);
            acc[ci][0] = __builtin_amdgcn_mfma_f32_16x16x32_bf16(af, bf0, acc[ci][0], 0, 0, 0);
            acc[ci][1] = __builtin_amdgcn_mfma_f32_16x16x32_bf16(af, bf1, acc[ci][1], 0, 0, 0);
        }
    }
    // q: reduce partial sums across quads (same l16)
    q0 += __shfl_xor(q0, 16); q0 += __shfl_xor(q0, 32);
    q1 += __shfl_xor(q1, 16); q1 += __shfl_xor(q1, 32);
    if (quad == 0) {
        if (v0) Q[row0] = q0;
        if (v1) Q[row1] = q1;
    }
    #pragma unroll
    for (int ci = 0; ci < 4; ++ci) {
        #pragma unroll
        for (int j = 0; j < 4; ++j) {
            int c = ci*16 + quad*4 + j;
            float s0 = q0 - 2.0f * acc[ci][0][j];
            float s1 = q1 - 2.0f * acc[ci][1][j];
            if (v0) S[(size_t)c*NB + row0] = s0;
            if (v1) S[(size_t)c*NB + row1] = s1;
            float mnv = fminf(v0 ? s0 : FLT_MAX,  v1 ? s1 : FLT_MAX);
            float mxv = fmaxf(v0 ? s0 : -FLT_MAX, v1 ? s1 : -FLT_MAX);
            #pragma unroll
            for (int o = 1; o < 16; o <<= 1) {
                mnv = fminf(mnv, __shfl_xor(mnv, o));
                mxv = fmaxf(mxv, __shfl_xor(mxv, o));
            }
            if (l16 == 0) {
                atomicMin(&lmn[c], f2ord(mnv));
                atomicMax(&lmx[c], f2ord(mxv));
            }
        }
    }
    __syncthreads();
    if (t < 64) {
        atomicMin(&mn_ord[t], lmn[t]);
        atomicMax(&mx_ord[t], lmx[t]);
    }
}

// ---------------- K10: per-concept 1024-bin histogram ----------------
__global__ void hist_kernel(const float* __restrict__ S,
                            const unsigned* __restrict__ mn_ord, const unsigned* __restrict__ mx_ord,
                            unsigned* __restrict__ hist) {
    __shared__ unsigned h[1024];
    int c = blockIdx.y, t = threadIdx.x;
    for (int i = t; i < 1024; i += 256) h[i] = 0u;
    float mnf = ord2f(mn_ord[c]);
    float mxf = ord2f(mx_ord[c]);
    float invw = (mxf > mnf) ? 1024.0f / (mxf - mnf) : 0.f;
    __syncthreads();
    const float4* s4 = (const float4*)(S + (size_t)c * NB);
    int base = blockIdx.x * 1024;
    #pragma unroll
    for (int j = 0; j < 4; ++j) {
        int idx = base + j*256 + t;
        if (idx < NB/4) {
            float4 v = s4[idx];
            float vv[4] = {v.x, v.y, v.z, v.w};
            #pragma unroll
            for (int e = 0; e < 4; ++e) {
                int b = (int)((vv[e] - mnf) * invw);
                b = b < 0 ? 0 : (b > 1023 ? 1023 : b);
                atomicAdd(&h[b], 1u);
            }
        }
    }
    __syncthreads();
    for (int i = t; i < 1024; i += 256)
        if (h[i]) atomicAdd(&hist[c*1024 + i], h[i]);
}

// ---------------- K11: per-concept scan (bins staged to LDS) ----------------
__global__ void scan_kernel(const unsigned* __restrict__ hist,
                            int* __restrict__ binB, int* __restrict__ nbel) {
    __shared__ unsigned h[1024];
    int c = blockIdx.x, t = threadIdx.x;
    for (int i = t; i < 1024; i += 256) h[i] = hist[c*1024 + i];
    __syncthreads();
    if (t == 0) {
        unsigned cum = 0; int B = 1023; unsigned below = 0;
        for (int b = 0; b < 1024; ++b) {
            unsigned hb = h[b];
            if (cum + hb >= TK) { B = b; below = cum; break; }
            cum += hb;
        }
        binB[c] = B;
        nbel[c] = (int)below;
    }
}

// ---------------- K12: collect — sum dots below B, gather bin-B candidates ----------------
__global__ void collect_kernel(const float* __restrict__ S, const float* __restrict__ Q,
                               const unsigned* __restrict__ mn_ord, const unsigned* __restrict__ mx_ord,
                               const int* __restrict__ binB,
                               int* __restrict__ ccnt, float* __restrict__ candv,
                               float* __restrict__ candd, float* __restrict__ psum) {
    __shared__ float red[256];
    int c = blockIdx.y, t = threadIdx.x;
    float mnf = ord2f(mn_ord[c]);
    float mxf = ord2f(mx_ord[c]);
    float invw = (mxf > mnf) ? 1024.0f / (mxf - mnf) : 0.f;
    int B = binB[c];
    const float4* s4 = (const float4*)(S + (size_t)c * NB);
    int base = blockIdx.x * 1024;
    float dsum = 0.f;
    #pragma unroll
    for (int j = 0; j < 4; ++j) {
        int idx = base + j*256 + t;
        if (idx < NB/4) {
            float4 v = s4[idx];
            float vv[4] = {v.x, v.y, v.z, v.w};
            #pragma unroll
            for (int e = 0; e < 4; ++e) {
                int b = (int)((vv[e] - mnf) * invw);
                b = b < 0 ? 0 : (b > 1023 ? 1023 : b);
                if (b < B) {
                    dsum += (Q[idx*4 + e] - vv[e]) * 0.5f;
                } else if (b == B) {
                    int p = atomicAdd(&ccnt[c], 1);
                    if (p < CAP) {
                        candv[c*CAP + p] = vv[e];
                        candd[c*CAP + p] = (Q[idx*4 + e] - vv[e]) * 0.5f;
                    }
                }
            }
        }
    }
    red[t] = dsum;
    __syncthreads();
    for (int s2 = 128; s2 > 0; s2 >>= 1) {
        if (t < s2) red[t] += red[t+s2];
        __syncthreads();
    }
    if (t == 0 && red[0] != 0.f) atomicAdd(&psum[c], red[0]);
}

// ---------------- K13: exact top among bin-B candidates ----------------
__global__ void final_kernel(const int* __restrict__ binB, const int* __restrict__ nbel,
                             const int* __restrict__ ccnt, const float* __restrict__ candv,
                             const float* __restrict__ candd, const float* __restrict__ psum,
                             float* __restrict__ out_l1) {
    __shared__ float v[CAP];
    __shared__ float dd[CAP];
    int c = blockIdx.x, t = threadIdx.x;   // 64 threads = 1 wave
    int M = ccnt[c]; if (M > CAP) M = CAP;
    int r = TK - nbel[c]; if (r > M) r = M;
    for (int i = t; i < M; i += 64) { v[i] = candv[c*CAP + i]; dd[i] = candd[c*CAP + i]; }
    __syncthreads();
    float sum = 0.f;
    for (int j = 0; j < r; ++j) {
        float bv = FLT_MAX; int bi = -1;
        for (int i = t; i < M; i += 64)
            if (v[i] < bv) { bv = v[i]; bi = i; }
        #pragma unroll
        for (int o = 32; o > 0; o >>= 1) {
            float ov = __shfl_down(bv, o);
            int   oi = __shfl_down(bi, o);
            if (ov < bv) { bv = ov; bi = oi; }
        }
        bi = __shfl(bi, 0);
        if (t == 0 && bi >= 0) { sum += dd[bi]; v[bi] = FLT_MAX; }
        __syncthreads();
    }
    if (t == 0) atomicAdd(out_l1, (sum + psum[c]) * (1.0f/4096.0f));
}

extern "C" void kernel_launch(void* const* d_in, const int* in_sizes, int n_in,
                              void* d_out, int out_size, void* d_ws, size_t ws_size,
                              hipStream_t stream) {
    const float* C  = (const float*)d_in[0];   // (512, 64)
    const float* E  = (const float*)d_in[1];   // (2048, 512)
    const float* Bk = (const float*)d_in[2];   // (200000, 512)
    const float* W  = (const float*)d_in[3];   // (512, 100)
    float* out = (float*)d_out;
    float* ws  = (float*)d_ws;

    float*    gram  = ws + W_GRAM;
    float*    ginv  = ws + W_GINV;
    float*    U     = ws + W_U;
    float*    H     = ws + W_H;
    float*    Q     = ws + W_Q;
    unsigned* mnord = (unsigned*)(ws + W_MIN);
    unsigned* mxord = (unsigned*)(ws + W_MAX);
    int*      binB  = (int*)(ws + W_BIN);
    int*      nbel  = (int*)(ws + W_NBEL);
    int*      ccnt  = (int*)(ws + W_CCNT);
    float*    psum  = ws + W_PSUM;
    unsigned* hist  = (unsigned*)(ws + W_HIST);
    float*    candv = ws + W_CANDV;
    float*    candd = ws + W_CANDD;
    short*    PA    = (short*)(ws + W_PACKA);
    short*    PB    = (short*)(ws + W_PACKB);
    float*    S     = ws + W_S;

    hipMemsetAsync(mnord, 0xFF, NC*4, stream);
    hipMemsetAsync(mxord, 0x00, NC*4, stream);
    hipMemsetAsync(hist,  0x00, NC*1024*4, stream);
    hipMemsetAsync(ccnt,  0x00, NC*4, stream);
    hipMemsetAsync(psum,  0x00, NC*4, stream);

    pack_kernel   <<<240,  256, 0, stream>>>(C, W, PA, PB);
    gram_kernel   <<<64,   64,  0, stream>>>(C, gram);
    scalars_kernel<<<1,    256, 0, stream>>>(gram, out + O_L1);
    invert_kernel <<<1,    512, 0, stream>>>(gram, ginv);
    u_kernel      <<<64,   128, 0, stream>>>(C, W, U);
    h_kernel      <<<64,   128, 0, stream>>>(ginv, U, H);
    ecw_kernel    <<<16,   256, 0, stream>>>(E, PB, out + O_CPRED, out + O_ORIG);
    ypred_kernel  <<<800,  256, 0, stream>>>(out + O_CPRED, H, out + O_YPRED);
    score_kernel  <<<(NB + 127)/128, 256, 0, stream>>>(Bk, PA, S, Q, mnord, mxord);

    dim3 hgrid(49, 64);
    hist_kernel   <<<hgrid, 256, 0, stream>>>(S, mnord, mxord, hist);
    scan_kernel   <<<64,   256, 0, stream>>>(hist, binB, nbel);
    collect_kernel<<<hgrid, 256, 0, stream>>>(S, Q, mnord, mxord, binB, ccnt, candv, candd, psum);
    final_kernel  <<<NC,   64,  0, stream>>>(binB, nbel, ccnt, candv, candd, psum, out + O_L1);
}